// Round 1
// baseline (4704.771 us; speedup 1.0000x reference)
//
#include <hip/hip_runtime.h>

// GCN 3-layer forward on MI355X.
// Strategy: fp32 atomics for deg + edge aggregation; self-loops folded into
// per-node kernels (no atomics needed); dis table (2MB) cache-resident so
// norm is recomputed per edge instead of materialized (saves 66MB/pass).

__global__ void k_deg(const int* __restrict__ dst, int E, float* __restrict__ deg) {
    int i = blockIdx.x * blockDim.x + threadIdx.x;
    if (i < E) atomicAdd(&deg[dst[i]], 1.0f);
}

__global__ void k_dis(float* __restrict__ deg, int N) {
    int i = blockIdx.x * blockDim.x + threadIdx.x;
    if (i < N) deg[i] = rsqrtf(deg[i] + 1.0f);   // +1 = self-loop; always > 0
}

// tmp[i,:] = x[i,:] @ W   (15x15), no bias (bias is added post-aggregation)
__global__ void k_lin_first(const float* __restrict__ x, const float* __restrict__ W,
                            float* __restrict__ tmp, int N) {
    int i = blockIdx.x * blockDim.x + threadIdx.x;
    if (i >= N) return;
    float in[15];
#pragma unroll
    for (int j = 0; j < 15; ++j) in[j] = x[i * 15 + j];
#pragma unroll
    for (int o = 0; o < 15; ++o) {
        float acc = 0.f;
#pragma unroll
        for (int j = 0; j < 15; ++j) acc = fmaf(in[j], W[j * 15 + o], acc);
        tmp[i * 15 + o] = acc;
    }
}

// h = relu(agg[i,:] + tmp[i,:]*dis[i]^2 + b)   (self-loop term folded in here)
// out[i,:] = h @ W   (15 x OUT)
template <int OUT>
__global__ void k_lin_mid(const float* __restrict__ agg, const float* __restrict__ tmp,
                          const float* __restrict__ dis, const float* __restrict__ W,
                          const float* __restrict__ b, float* __restrict__ out, int N) {
    int i = blockIdx.x * blockDim.x + threadIdx.x;
    if (i >= N) return;
    float d2 = dis[i];
    d2 *= d2;
    float in[15];
#pragma unroll
    for (int j = 0; j < 15; ++j) {
        float v = agg[i * 15 + j] + tmp[i * 15 + j] * d2 + b[j];
        in[j] = v > 0.f ? v : 0.f;
    }
#pragma unroll
    for (int o = 0; o < OUT; ++o) {
        float acc = 0.f;
#pragma unroll
        for (int j = 0; j < 15; ++j) acc = fmaf(in[j], W[j * OUT + o], acc);
        out[i * OUT + o] = acc;
    }
}

// out[i,o] = b3[o] + tmp[i,o]*dis[i]^2   (layer-3 bias + self-loop init)
__global__ void k_out_init(const float* __restrict__ tmp, const float* __restrict__ dis,
                           const float* __restrict__ b, float* __restrict__ out, int N) {
    int t = blockIdx.x * blockDim.x + threadIdx.x;
    int i = t >> 2, o = t & 3;
    if (i >= N) return;
    float d = dis[i];
    out[i * 4 + o] = b[o] + tmp[i * 4 + o] * d * d;
}

// Edge aggregation, 15 features: 16 lanes per edge (lane j<15 = feature j).
// h-row gather is 60B contiguous per edge; atomics hit consecutive dwords.
__global__ void k_scatter15(const int* __restrict__ src, const int* __restrict__ dst,
                            const float* __restrict__ h, const float* __restrict__ dis,
                            float* __restrict__ out, int E) {
    int t = blockIdx.x * blockDim.x + threadIdx.x;
    int e = t >> 4;
    int j = t & 15;
    if (e >= E || j >= 15) return;
    int s = src[e], d = dst[e];
    float nrm = dis[s] * dis[d];
    atomicAdd(&out[d * 15 + j], h[s * 15 + j] * nrm);
}

// Edge aggregation, 4 features: 4 lanes per edge (all lanes active).
__global__ void k_scatter4(const int* __restrict__ src, const int* __restrict__ dst,
                           const float* __restrict__ h, const float* __restrict__ dis,
                           float* __restrict__ out, int E) {
    int t = blockIdx.x * blockDim.x + threadIdx.x;
    int e = t >> 2;
    int j = t & 3;
    if (e >= E) return;
    int s = src[e], d = dst[e];
    float nrm = dis[s] * dis[d];
    atomicAdd(&out[d * 4 + j], h[s * 4 + j] * nrm);
}

extern "C" void kernel_launch(void* const* d_in, const int* in_sizes, int n_in,
                              void* d_out, int out_size, void* d_ws, size_t ws_size,
                              hipStream_t stream) {
    const float* x  = (const float*)d_in[0];
    const int*   ei = (const int*)d_in[1];
    // d_in[2] = batch_index (unused by reference)
    const float* W1 = (const float*)d_in[3];
    const float* b1 = (const float*)d_in[4];
    const float* W2 = (const float*)d_in[5];
    const float* b2 = (const float*)d_in[6];
    const float* W3 = (const float*)d_in[7];
    const float* b3 = (const float*)d_in[8];
    float* out = (float*)d_out;

    const int N = in_sizes[0] / 15;
    const int E = in_sizes[1] / 2;
    const int* src = ei;
    const int* dst = ei + E;

    // Workspace layout: dis (N f32) | A (N*15 f32) | B (N*15) | C (N*15)
    char* ws = (char*)d_ws;
    const size_t AL   = 256;
    const size_t disB = (((size_t)N * 4) + AL - 1) / AL * AL;
    const size_t rowB = (((size_t)N * 15 * 4) + AL - 1) / AL * AL;
    float* dis = (float*)ws;
    float* A   = (float*)(ws + disB);
    float* B   = (float*)(ws + disB + rowB);
    float* C   = (float*)(ws + disB + 2 * rowB);

    const int TB = 256;
    const int nBlkN   = (N + TB - 1) / TB;
    const int nBlkE   = (E + TB - 1) / TB;
    const int nBlkE16 = (int)(((long long)E * 16 + TB - 1) / TB);
    const int nBlkE4  = (int)(((long long)E * 4 + TB - 1) / TB);
    const int nBlkN4  = (int)(((long long)N * 4 + TB - 1) / TB);

    // Degree + normalization table
    hipMemsetAsync(dis, 0, (size_t)N * 4, stream);
    k_deg<<<nBlkE, TB, 0, stream>>>(dst, E, dis);
    k_dis<<<nBlkN, TB, 0, stream>>>(dis, N);

    // Layer 1: A = x@W1 ; B = scatter(A)
    k_lin_first<<<nBlkN, TB, 0, stream>>>(x, W1, A, N);
    hipMemsetAsync(B, 0, (size_t)N * 15 * 4, stream);
    k_scatter15<<<nBlkE16, TB, 0, stream>>>(src, dst, A, dis, B, E);

    // Layer 2: C = relu(B + A*dis^2 + b1) @ W2 ; A = scatter(C)
    k_lin_mid<15><<<nBlkN, TB, 0, stream>>>(B, A, dis, W2, b1, C, N);
    hipMemsetAsync(A, 0, (size_t)N * 15 * 4, stream);
    k_scatter15<<<nBlkE16, TB, 0, stream>>>(src, dst, C, dis, A, E);

    // Layer 3: B = relu(A + C*dis^2 + b2) @ W3 (N x 4) ; out = b3 + self + scatter(B)
    k_lin_mid<4><<<nBlkN, TB, 0, stream>>>(A, C, dis, W3, b2, B, N);
    k_out_init<<<nBlkN4, TB, 0, stream>>>(B, dis, b3, out, N);
    k_scatter4<<<nBlkE4, TB, 0, stream>>>(src, dst, B, dis, out, E);
}

// Round 2
// 3169.362 us; speedup vs baseline: 1.4845x; 1.4845x over previous
//
#include <hip/hip_runtime.h>

// GCN 3-layer forward, CSR pull-aggregation (no atomics in the hot passes).
// R2: push-scatter w/ fp32 atomics cost 3.3GB traffic/pass (1.9GB gather-line
// fetch + 1.4GB atomic write-through). Pull over dst-sorted CSR removes the
// atomic writes; 64B-padded rows make each gather exactly one L2 line.

typedef unsigned int uint;

// ---- CSR build ----
__global__ void k_deg(const int* __restrict__ dst, int E, uint* __restrict__ cnt) {
    int i = blockIdx.x * blockDim.x + threadIdx.x;
    if (i < E) atomicAdd(&cnt[dst[i]], 1u);
}

// per-256-block sums of cnt
__global__ void k_bsum(const uint* __restrict__ cnt, int N, uint* __restrict__ bsum) {
    __shared__ uint s[256];
    int t = threadIdx.x;
    int i = blockIdx.x * 256 + t;
    s[t] = (i < N) ? cnt[i] : 0u;
    __syncthreads();
    for (int off = 128; off > 0; off >>= 1) {
        if (t < off) s[t] += s[t + off];
        __syncthreads();
    }
    if (t == 0) bsum[blockIdx.x] = s[0];
}

// exclusive-scan bsum in place (single block, 256 threads, serial chunks)
__global__ void k_scan_bsum(uint* __restrict__ bsum, int nb) {
    __shared__ uint s[256];
    int t = threadIdx.x;
    int c = (nb + 255) / 256;
    int k0 = t * c, k1 = min(k0 + c, nb);
    uint sum = 0;
    for (int k = k0; k < k1; ++k) sum += bsum[k];
    s[t] = sum;
    __syncthreads();
    for (int off = 1; off < 256; off <<= 1) {
        uint x = (t >= off) ? s[t - off] : 0u;
        __syncthreads();
        s[t] += x;
        __syncthreads();
    }
    uint run = s[t] - sum;  // exclusive base of this chunk
    for (int k = k0; k < k1; ++k) {
        uint v = bsum[k];
        bsum[k] = run;
        run += v;
    }
}

// row_ptr (exclusive scan of cnt), cursor copy, dis = rsqrt(deg+1)
__global__ void k_rowptr(const uint* __restrict__ cnt, const uint* __restrict__ bsumEx,
                         int N, uint* __restrict__ rowp, uint* __restrict__ cursor,
                         float* __restrict__ dis) {
    __shared__ uint s[256];
    int t = threadIdx.x;
    int i = blockIdx.x * 256 + t;
    uint v = (i < N) ? cnt[i] : 0u;
    s[t] = v;
    __syncthreads();
    for (int off = 1; off < 256; off <<= 1) {
        uint x = (t >= off) ? s[t - off] : 0u;
        __syncthreads();
        s[t] += x;
        __syncthreads();
    }
    if (i < N) {
        uint rp = bsumEx[blockIdx.x] + s[t] - v;  // exclusive
        rowp[i] = rp;
        cursor[i] = rp;
        dis[i] = rsqrtf((float)(v + 1u));  // +1 self-loop, always > 0
        if (i == N - 1) rowp[N] = rp + v;
    }
}

__global__ void k_fill(const int* __restrict__ src, const int* __restrict__ dst, int E,
                       uint* __restrict__ cursor, int* __restrict__ srcS) {
    int e = blockIdx.x * blockDim.x + threadIdx.x;
    if (e >= E) return;
    uint pos = atomicAdd(&cursor[dst[e]], 1u);
    srcS[pos] = src[e];
}

// ---- dense per-node transforms ----
// A[i,0:15] = x[i,:] @ W1 ; A[i,15] = 0   (rows padded to 64B)
__global__ void k_lin_first(const float* __restrict__ x, const float* __restrict__ W,
                            float* __restrict__ A, int N) {
    int i = blockIdx.x * blockDim.x + threadIdx.x;
    if (i >= N) return;
    float in[15];
#pragma unroll
    for (int j = 0; j < 15; ++j) in[j] = x[i * 15 + j];
#pragma unroll
    for (int o = 0; o < 15; ++o) {
        float acc = 0.f;
#pragma unroll
        for (int j = 0; j < 15; ++j) acc = fmaf(in[j], W[j * 15 + o], acc);
        A[i * 16 + o] = acc;
    }
    A[i * 16 + 15] = 0.f;
}

// ---- fused pull: agg(H) -> +bias -> relu -> @W -> out ----
// 16 lanes per node (lane j = feature j; lane 15 idle on the gather value).
// Gathers read one full 64B line per edge. Epilogue transposes via LDS
// (same-wave, but block barrier is once per thread lifetime — free).
template <int OUT>
__global__ void k_pull_mm(const float* __restrict__ H, const int* __restrict__ srcS,
                          const uint* __restrict__ rowp, const float* __restrict__ dis,
                          const float* __restrict__ W,   // 15 x OUT
                          const float* __restrict__ b,   // 15, pre-relu bias
                          float* __restrict__ outBuf, int OS, int N) {
    __shared__ float v[16 * 16];
    int tid = blockIdx.x * blockDim.x + threadIdx.x;
    int node = tid >> 4;
    int j = tid & 15;
    int local = threadIdx.x >> 4;
    bool valid = node < N;
    if (valid) {
        float dis_i = dis[node];
        float acc = H[node * 16 + j] * dis_i * dis_i;  // self-loop (pad col = 0)
        uint e = rowp[node], rend = rowp[node + 1];
        for (; e + 2 <= rend; e += 2) {               // 2x unroll: 2 gathers in flight
            int s0 = srcS[e], s1 = srcS[e + 1];
            float w0 = dis[s0] * dis_i, w1 = dis[s1] * dis_i;
            float h0 = H[s0 * 16 + j], h1 = H[s1 * 16 + j];
            acc = fmaf(h0, w0, acc);
            acc = fmaf(h1, w1, acc);
        }
        if (e < rend) {
            int s0 = srcS[e];
            acc = fmaf(H[s0 * 16 + j], dis[s0] * dis_i, acc);
        }
        float val = (j < 15) ? (acc + b[j]) : 0.f;
        v[local * 16 + j] = val > 0.f ? val : 0.f;     // relu
    } else {
        v[local * 16 + j] = 0.f;
    }
    __syncthreads();
    if (valid) {
        if (j < OUT) {
            float o = 0.f;
#pragma unroll
            for (int k = 0; k < 15; ++k) o = fmaf(v[local * 16 + k], W[k * OUT + j], o);
            outBuf[(size_t)node * OS + j] = o;
        }
        if (OUT == 15 && j == 15) outBuf[(size_t)node * OS + 15] = 0.f;
    }
}

// final pull over 4-dim C: out = agg(C) + b3   (4 lanes/node, no relu/matmul)
__global__ void k_pull_final(const float* __restrict__ C4, const int* __restrict__ srcS,
                             const uint* __restrict__ rowp, const float* __restrict__ dis,
                             const float* __restrict__ b3, float* __restrict__ out, int N) {
    int tid = blockIdx.x * blockDim.x + threadIdx.x;
    int node = tid >> 2;
    int j = tid & 3;
    if (node >= N) return;
    float dis_i = dis[node];
    float acc = C4[(size_t)node * 4 + j] * dis_i * dis_i;
    uint e = rowp[node], rend = rowp[node + 1];
    for (; e + 2 <= rend; e += 2) {
        int s0 = srcS[e], s1 = srcS[e + 1];
        float w0 = dis[s0] * dis_i, w1 = dis[s1] * dis_i;
        float h0 = C4[(size_t)s0 * 4 + j], h1 = C4[(size_t)s1 * 4 + j];
        acc = fmaf(h0, w0, acc);
        acc = fmaf(h1, w1, acc);
    }
    if (e < rend) {
        int s0 = srcS[e];
        acc = fmaf(C4[(size_t)s0 * 4 + j], dis[s0] * dis_i, acc);
    }
    out[(size_t)node * 4 + j] = acc + b3[j];
}

extern "C" void kernel_launch(void* const* d_in, const int* in_sizes, int n_in,
                              void* d_out, int out_size, void* d_ws, size_t ws_size,
                              hipStream_t stream) {
    const float* x  = (const float*)d_in[0];
    const int*   ei = (const int*)d_in[1];
    const float* W1 = (const float*)d_in[3];
    const float* b1 = (const float*)d_in[4];
    const float* W2 = (const float*)d_in[5];
    const float* b2 = (const float*)d_in[6];
    const float* W3 = (const float*)d_in[7];
    const float* b3 = (const float*)d_in[8];
    float* out = (float*)d_out;

    const int N = in_sizes[0] / 15;
    const int E = in_sizes[1] / 2;
    const int* src = ei;
    const int* dst = ei + E;
    const int nb = (N + 255) / 256;  // #256-blocks over nodes

    // Workspace layout (256B aligned slabs)
    char* ws = (char*)d_ws;
    auto align = [](size_t v) { return (v + 255) & ~(size_t)255; };
    size_t off = 0;
    uint* cnt    = (uint*)(ws + off); off += align((size_t)N * 4);
    uint* rowp   = (uint*)(ws + off); off += align((size_t)(N + 1) * 4);
    uint* cursor = (uint*)(ws + off); off += align((size_t)N * 4);
    uint* bsum   = (uint*)(ws + off); off += align((size_t)nb * 4);
    float* dis   = (float*)(ws + off); off += align((size_t)N * 4);
    int*  srcS   = (int*)(ws + off);  off += align((size_t)E * 4);
    float* A     = (float*)(ws + off); off += align((size_t)N * 16 * 4);
    float* B     = (float*)(ws + off); off += align((size_t)N * 16 * 4);
    float* C     = A;  // A dead once layer-2 pull starts; reuse as 4-dim C

    const int TB = 256;
    const int gE  = (E + TB - 1) / TB;
    const int gN16 = (int)(((long long)N * 16 + TB - 1) / TB);
    const int gN4  = (int)(((long long)N * 4 + TB - 1) / TB);

    // CSR build (by dst) + dis table
    hipMemsetAsync(cnt, 0, (size_t)N * 4, stream);
    k_deg<<<gE, TB, 0, stream>>>(dst, E, cnt);
    k_bsum<<<nb, TB, 0, stream>>>(cnt, N, bsum);
    k_scan_bsum<<<1, TB, 0, stream>>>(bsum, nb);
    k_rowptr<<<nb, TB, 0, stream>>>(cnt, bsum, N, rowp, cursor, dis);
    k_fill<<<gE, TB, 0, stream>>>(src, dst, E, cursor, srcS);

    // Layer 1 input transform
    k_lin_first<<<nb, TB, 0, stream>>>(x, W1, A, N);

    // Fused pulls: [agg -> +b -> relu -> @W]
    k_pull_mm<15><<<gN16, TB, 0, stream>>>(A, srcS, rowp, dis, W2, b1, B, 16, N);
    k_pull_mm<4><<<gN16, TB, 0, stream>>>(B, srcS, rowp, dis, W3, b2, C, 4, N);
    k_pull_final<<<gN4, TB, 0, stream>>>(C, srcS, rowp, dis, b3, out, N);
}

// Round 3
// 1696.216 us; speedup vs baseline: 2.7737x; 1.8685x over previous
//
#include <hip/hip_runtime.h>

// GCN 3-layer forward. CSR pull (R2) + bucketed CSR build (R3).
// R2 lesson: k_fill's random 4B scatter cost 990MB HBM writes (16x amp).
// R3: two-level partition. bucket = dst>>10 (<=1024 nodes). LDS-staged radix
// partition -> per-bucket blocks build deg/CSR with LDS counters only.
// All HBM traffic coalesced; scatters confined to L2-resident regions.

typedef unsigned int uint;
typedef unsigned short ushort;

#define NB 512            // bucket count (dst >> 10; 489 live for N=500K)
#define PT_THREADS 512
#define PT_TILE 8192      // edges per partition tile (16 per thread)

// ---- bucket histogram ----
__global__ void k_hist(const int* __restrict__ dst, int E, uint* __restrict__ bcnt) {
    __shared__ uint h[NB];
    int t = threadIdx.x;
    for (int i = t; i < NB; i += 256) h[i] = 0;
    __syncthreads();
    for (long long e = (long long)blockIdx.x * 256 + t; e < E; e += (long long)gridDim.x * 256)
        atomicAdd(&h[((uint)dst[e]) >> 10], 1u);
    __syncthreads();
    for (int i = t; i < NB; i += 256) if (h[i]) atomicAdd(&bcnt[i], h[i]);
}

// single block, NB threads: exclusive scan -> bbase[0..NB], init gcur
__global__ void k_scan_buckets(const uint* __restrict__ bcnt, uint* __restrict__ bbase,
                               uint* __restrict__ gcur) {
    __shared__ uint s[NB];
    int t = threadIdx.x;
    uint v = bcnt[t];
    s[t] = v;
    __syncthreads();
    for (int off = 1; off < NB; off <<= 1) {
        uint x = (t >= off) ? s[t - off] : 0u;
        __syncthreads();
        s[t] += x;
        __syncthreads();
    }
    uint ex = s[t] - v;
    bbase[t] = ex;
    gcur[t] = ex;
    if (t == NB - 1) bbase[NB] = s[t];
}

// ---- LDS-staged partition: edges -> bucketed (packed src|dstLocal<<19) ----
__global__ __launch_bounds__(PT_THREADS) void k_part(const int* __restrict__ src,
                                                     const int* __restrict__ dst, int E,
                                                     uint* __restrict__ gcur,
                                                     uint* __restrict__ bucketed) {
    __shared__ uint stage[PT_TILE];
    __shared__ ushort sbuck[PT_TILE];
    __shared__ uint hist[NB];
    __shared__ uint lofs[NB];   // scan buffer -> exclusive offsets
    __shared__ uint base[NB];   // global segment base for this tile
    int t = threadIdx.x;
    long long start = (long long)blockIdx.x * PT_TILE;
    int cnt = (int)min((long long)PT_TILE, (long long)E - start);

    for (int i = t; i < NB; i += PT_THREADS) hist[i] = 0;
    __syncthreads();

    uint myb[16], myr[16], mys[16];
#pragma unroll
    for (int k = 0; k < 16; ++k) {
        int idx = t + k * PT_THREADS;
        if (idx < cnt) {
            uint d = (uint)dst[start + idx];
            uint s = (uint)src[start + idx];
            uint b = d >> 10;
            myb[k] = b;
            mys[k] = s | ((d & 1023u) << 19);
            myr[k] = atomicAdd(&hist[b], 1u);
        }
    }
    __syncthreads();
    // exclusive scan of hist into lofs (PT_THREADS == NB)
    uint v = hist[t];
    lofs[t] = v;
    __syncthreads();
    for (int off = 1; off < NB; off <<= 1) {
        uint x = (t >= off) ? lofs[t - off] : 0u;
        __syncthreads();
        lofs[t] += x;
        __syncthreads();
    }
    uint ex = lofs[t] - v;
    __syncthreads();
    lofs[t] = ex;
    base[t] = atomicAdd(&gcur[t], v);   // reserve global run for this tile
    __syncthreads();
    // stage bucket-ordered
#pragma unroll
    for (int k = 0; k < 16; ++k) {
        int idx = t + k * PT_THREADS;
        if (idx < cnt) {
            uint pos = lofs[myb[k]] + myr[k];
            stage[pos] = mys[k];
            sbuck[pos] = (ushort)myb[k];
        }
    }
    __syncthreads();
    // coalesced-run output
#pragma unroll
    for (int k = 0; k < 16; ++k) {
        int idx = t + k * PT_THREADS;
        if (idx < cnt) {
            uint b = sbuck[idx];
            bucketed[base[b] + ((uint)idx - lofs[b])] = stage[idx];
        }
    }
}

// ---- per-bucket degree (LDS counters, zero global atomics) ----
__global__ void k_deg2(const uint* __restrict__ bucketed, const uint* __restrict__ bbase,
                       uint* __restrict__ cnt, int N) {
    __shared__ uint c[1024];
    int b = blockIdx.x, t = threadIdx.x;
    for (int i = t; i < 1024; i += 256) c[i] = 0;
    __syncthreads();
    uint beg = bbase[b], end = bbase[b + 1];
    for (uint e = beg + t; e < end; e += 256) atomicAdd(&c[bucketed[e] >> 19], 1u);
    __syncthreads();
    int nodeBase = b << 10;
    for (int i = t; i < 1024; i += 256) {
        int node = nodeBase + i;
        if (node < N) cnt[node] = c[i];
    }
}

// ---- node-level scan machinery (rowp) ----
__global__ void k_bsum(const uint* __restrict__ cnt, int N, uint* __restrict__ bsum) {
    __shared__ uint s[256];
    int t = threadIdx.x;
    int i = blockIdx.x * 256 + t;
    s[t] = (i < N) ? cnt[i] : 0u;
    __syncthreads();
    for (int off = 128; off > 0; off >>= 1) {
        if (t < off) s[t] += s[t + off];
        __syncthreads();
    }
    if (t == 0) bsum[blockIdx.x] = s[0];
}

__global__ void k_scan_bsum(uint* __restrict__ bsum, int nb) {
    __shared__ uint s[256];
    int t = threadIdx.x;
    int c = (nb + 255) / 256;
    int k0 = t * c, k1 = min(k0 + c, nb);
    uint sum = 0;
    for (int k = k0; k < k1; ++k) sum += bsum[k];
    s[t] = sum;
    __syncthreads();
    for (int off = 1; off < 256; off <<= 1) {
        uint x = (t >= off) ? s[t - off] : 0u;
        __syncthreads();
        s[t] += x;
        __syncthreads();
    }
    uint run = s[t] - sum;
    for (int k = k0; k < k1; ++k) {
        uint v = bsum[k];
        bsum[k] = run;
        run += v;
    }
}

__global__ void k_rowptr(const uint* __restrict__ cnt, const uint* __restrict__ bsumEx,
                         int N, uint* __restrict__ rowp, float* __restrict__ dis) {
    __shared__ uint s[256];
    int t = threadIdx.x;
    int i = blockIdx.x * 256 + t;
    uint v = (i < N) ? cnt[i] : 0u;
    s[t] = v;
    __syncthreads();
    for (int off = 1; off < 256; off <<= 1) {
        uint x = (t >= off) ? s[t - off] : 0u;
        __syncthreads();
        s[t] += x;
        __syncthreads();
    }
    if (i < N) {
        uint rp = bsumEx[blockIdx.x] + s[t] - v;
        rowp[i] = rp;
        dis[i] = rsqrtf((float)(v + 1u));
        if (i == N - 1) rowp[N] = rp + v;
    }
}

// ---- per-bucket CSR fill (LDS cursors; one block owns one bucket) ----
__global__ void k_fill2(const uint* __restrict__ bucketed, const uint* __restrict__ bbase,
                        const uint* __restrict__ rowp, int* __restrict__ srcS, int N) {
    __shared__ uint cur[1024];
    int b = blockIdx.x, t = threadIdx.x;
    int nodeBase = b << 10;
    for (int i = t; i < 1024; i += 256) {
        int node = nodeBase + i;
        cur[i] = (node < N) ? rowp[node] : 0u;
    }
    __syncthreads();
    uint beg = bbase[b], end = bbase[b + 1];
    for (uint e = beg + t; e < end; e += 256) {
        uint v = bucketed[e];
        uint pos = atomicAdd(&cur[v >> 19], 1u);
        srcS[pos] = (int)(v & 0x7ffffu);
    }
}

// ---- dense per-node transform: A[i,0:15] = x[i,:]@W1, A[i,15]=0 ----
__global__ void k_lin_first(const float* __restrict__ x, const float* __restrict__ W,
                            float* __restrict__ A, int N) {
    int i = blockIdx.x * blockDim.x + threadIdx.x;
    if (i >= N) return;
    float in[15];
#pragma unroll
    for (int j = 0; j < 15; ++j) in[j] = x[i * 15 + j];
#pragma unroll
    for (int o = 0; o < 15; ++o) {
        float acc = 0.f;
#pragma unroll
        for (int j = 0; j < 15; ++j) acc = fmaf(in[j], W[j * 15 + o], acc);
        A[i * 16 + o] = acc;
    }
    A[i * 16 + 15] = 0.f;
}

// ---- fused pull: agg(H) -> +bias -> relu -> @W -> out (16 lanes/node) ----
template <int OUT>
__global__ void k_pull_mm(const float* __restrict__ H, const int* __restrict__ srcS,
                          const uint* __restrict__ rowp, const float* __restrict__ dis,
                          const float* __restrict__ W, const float* __restrict__ b,
                          float* __restrict__ outBuf, int OS, int N) {
    __shared__ float v[16 * 16];
    int tid = blockIdx.x * blockDim.x + threadIdx.x;
    int node = tid >> 4;
    int j = tid & 15;
    int local = threadIdx.x >> 4;
    bool valid = node < N;
    if (valid) {
        float dis_i = dis[node];
        float acc = H[node * 16 + j] * dis_i * dis_i;  // self-loop
        uint e = rowp[node], rend = rowp[node + 1];
        for (; e + 2 <= rend; e += 2) {
            int s0 = srcS[e], s1 = srcS[e + 1];
            float w0 = dis[s0] * dis_i, w1 = dis[s1] * dis_i;
            float h0 = H[s0 * 16 + j], h1 = H[s1 * 16 + j];
            acc = fmaf(h0, w0, acc);
            acc = fmaf(h1, w1, acc);
        }
        if (e < rend) {
            int s0 = srcS[e];
            acc = fmaf(H[s0 * 16 + j], dis[s0] * dis_i, acc);
        }
        float val = (j < 15) ? (acc + b[j]) : 0.f;
        v[local * 16 + j] = val > 0.f ? val : 0.f;
    } else {
        v[local * 16 + j] = 0.f;
    }
    __syncthreads();
    if (valid) {
        if (j < OUT) {
            float o = 0.f;
#pragma unroll
            for (int k = 0; k < 15; ++k) o = fmaf(v[local * 16 + k], W[k * OUT + j], o);
            outBuf[(size_t)node * OS + j] = o;
        }
        if (OUT == 15 && j == 15) outBuf[(size_t)node * OS + 15] = 0.f;
    }
}

// ---- final pull over 4-dim C ----
__global__ void k_pull_final(const float* __restrict__ C4, const int* __restrict__ srcS,
                             const uint* __restrict__ rowp, const float* __restrict__ dis,
                             const float* __restrict__ b3, float* __restrict__ out, int N) {
    int tid = blockIdx.x * blockDim.x + threadIdx.x;
    int node = tid >> 2;
    int j = tid & 3;
    if (node >= N) return;
    float dis_i = dis[node];
    float acc = C4[(size_t)node * 4 + j] * dis_i * dis_i;
    uint e = rowp[node], rend = rowp[node + 1];
    for (; e + 2 <= rend; e += 2) {
        int s0 = srcS[e], s1 = srcS[e + 1];
        float w0 = dis[s0] * dis_i, w1 = dis[s1] * dis_i;
        acc = fmaf(C4[(size_t)s0 * 4 + j], w0, acc);
        acc = fmaf(C4[(size_t)s1 * 4 + j], w1, acc);
    }
    if (e < rend) {
        int s0 = srcS[e];
        acc = fmaf(C4[(size_t)s0 * 4 + j], dis[s0] * dis_i, acc);
    }
    out[(size_t)node * 4 + j] = acc + b3[j];
}

extern "C" void kernel_launch(void* const* d_in, const int* in_sizes, int n_in,
                              void* d_out, int out_size, void* d_ws, size_t ws_size,
                              hipStream_t stream) {
    const float* x  = (const float*)d_in[0];
    const int*   ei = (const int*)d_in[1];
    const float* W1 = (const float*)d_in[3];
    const float* b1 = (const float*)d_in[4];
    const float* W2 = (const float*)d_in[5];
    const float* b2 = (const float*)d_in[6];
    const float* W3 = (const float*)d_in[7];
    const float* b3 = (const float*)d_in[8];
    float* out = (float*)d_out;

    const int N = in_sizes[0] / 15;
    const int E = in_sizes[1] / 2;
    const int* src = ei;
    const int* dst = ei + E;
    const int nb  = (N + 255) / 256;        // node scan blocks
    const int NBr = (N + 1023) >> 10;       // live buckets (489)

    // Workspace layout (256B-aligned). bucketed (64MB) aliased by A+B (dead after fill2).
    char* ws = (char*)d_ws;
    auto align = [](size_t v) { return (v + 255) & ~(size_t)255; };
    size_t off = 0;
    uint* cnt   = (uint*)(ws + off); off += align((size_t)N * 4);
    uint* rowp  = (uint*)(ws + off); off += align((size_t)(N + 1) * 4);
    uint* bsum  = (uint*)(ws + off); off += align((size_t)nb * 4);
    float* dis  = (float*)(ws + off); off += align((size_t)N * 4);
    uint* bcnt  = (uint*)(ws + off); off += align((size_t)NB * 4);
    uint* bbase = (uint*)(ws + off); off += align((size_t)(NB + 1) * 4);
    uint* gcur  = (uint*)(ws + off); off += align((size_t)NB * 4);
    int*  srcS  = (int*)(ws + off);  off += align((size_t)E * 4);
    uint* bucketed = (uint*)(ws + off);            // 64 MB, dead after k_fill2
    float* A    = (float*)(ws + off); off += align((size_t)N * 16 * 4);
    float* B    = (float*)(ws + off); off += align((size_t)N * 16 * 4);
    float* C    = A;  // 4-wide, reuse

    const int TB = 256;
    const int nTiles = (int)(((long long)E + PT_TILE - 1) / PT_TILE);
    const int gN16 = (int)(((long long)N * 16 + TB - 1) / TB);
    const int gN4  = (int)(((long long)N * 4 + TB - 1) / TB);

    // CSR build via bucket partition
    hipMemsetAsync(bcnt, 0, (size_t)NB * 4, stream);
    k_hist<<<2048, TB, 0, stream>>>(dst, E, bcnt);
    k_scan_buckets<<<1, NB, 0, stream>>>(bcnt, bbase, gcur);
    k_part<<<nTiles, PT_THREADS, 0, stream>>>(src, dst, E, gcur, bucketed);
    k_deg2<<<NBr, TB, 0, stream>>>(bucketed, bbase, cnt, N);
    k_bsum<<<nb, TB, 0, stream>>>(cnt, N, bsum);
    k_scan_bsum<<<1, TB, 0, stream>>>(bsum, nb);
    k_rowptr<<<nb, TB, 0, stream>>>(cnt, bsum, N, rowp, dis);
    k_fill2<<<NBr, TB, 0, stream>>>(bucketed, bbase, rowp, srcS, N);

    // Layers
    k_lin_first<<<nb, TB, 0, stream>>>(x, W1, A, N);
    k_pull_mm<15><<<gN16, TB, 0, stream>>>(A, srcS, rowp, dis, W2, b1, B, 16, N);
    k_pull_mm<4><<<gN16, TB, 0, stream>>>(B, srcS, rowp, dis, W3, b2, C, 4, N);
    k_pull_final<<<gN4, TB, 0, stream>>>(C, srcS, rowp, dis, b3, out, N);
}